// Round 11
// baseline (778.040 us; speedup 1.0000x reference)
//
#include <hip/hip_runtime.h>
#include <hip/hip_bf16.h>

#define N_ROWS 4096
#define H_DIM  512
#define V_DIM  50257
#define BM 128
#define BN 128
#define BK 32
#define NSTEP 16
#define VT_TOTAL 393            // ceil(V/BN)
#define V_PAD (VT_TOTAL * BN)   // 50304
#define NCHUNK 131              // 393 = 3*131 -> every block exactly 3 tiles
#define LOG2E 1.4426950408889634f
#define LOFF 49152              // L half-tile (bf16, 16 KB) = buffer 3 region

#define LGKM0()  asm volatile("s_waitcnt lgkmcnt(0)" ::: "memory")
#define VMC0()   asm volatile("s_waitcnt vmcnt(0)" ::: "memory")
#define BARRIER() __builtin_amdgcn_s_barrier()

typedef __attribute__((ext_vector_type(8))) short short8;
typedef __attribute__((ext_vector_type(4))) float f32x4;

template <int N>
static __device__ __forceinline__ void vmw() {
  if constexpr (N == 0)       asm volatile("s_waitcnt vmcnt(0)" ::: "memory");
  else if constexpr (N == 4)  asm volatile("s_waitcnt vmcnt(4)" ::: "memory");
  else if constexpr (N == 8)  asm volatile("s_waitcnt vmcnt(8)" ::: "memory");
  else                        asm volatile("s_waitcnt vmcnt(12)" ::: "memory");
}

static __device__ __forceinline__ unsigned short f2bf(float f) {
  unsigned u = __float_as_uint(f);
  u = (u + 0x7fffu + ((u >> 16) & 1u)) >> 16;   // RNE
  return (unsigned short)u;
}

static __device__ __forceinline__ void gload_lds16(const void* g, void* l) {
  __builtin_amdgcn_global_load_lds(
      (const __attribute__((address_space(1))) void*)g,
      (__attribute__((address_space(3))) void*)l, 16, 0, 0);
}

// ---------------- kernel A: fp32 -> bf16 conversion (W padded to V_PAD) ----
__global__ void convert_kernel(const float* __restrict__ X,
                               const float* __restrict__ W,
                               __hip_bfloat16* __restrict__ Xb,
                               __hip_bfloat16* __restrict__ Wb) {
  const long wtot8 = (long)V_PAD * H_DIM / 8;   // 3,219,456
  const long xtot8 = (long)N_ROWS * H_DIM / 8;  //   262,144
  long i = (long)blockIdx.x * blockDim.x + threadIdx.x;
  unsigned short o[8];
  if (i < wtot8) {
    long base = i * 8;
    long row = base >> 9;   // /512
    if (row < V_DIM) {
      const float4* s = (const float4*)(W + base);
      float4 a = s[0], b = s[1];
      o[0]=f2bf(a.x); o[1]=f2bf(a.y); o[2]=f2bf(a.z); o[3]=f2bf(a.w);
      o[4]=f2bf(b.x); o[5]=f2bf(b.y); o[6]=f2bf(b.z); o[7]=f2bf(b.w);
    } else {
      #pragma unroll
      for (int k = 0; k < 8; ++k) o[k] = 0;
    }
    *(short8*)(Wb + base) = *(const short8*)o;
  } else if (i < wtot8 + xtot8) {
    long base = (i - wtot8) * 8;
    const float4* s = (const float4*)(X + base);
    float4 a = s[0], b = s[1];
    o[0]=f2bf(a.x); o[1]=f2bf(a.y); o[2]=f2bf(a.z); o[3]=f2bf(a.w);
    o[4]=f2bf(b.x); o[5]=f2bf(b.y); o[6]=f2bf(b.z); o[7]=f2bf(b.w);
    *(short8*)(Xb + base) = *(const short8*)o;
  }
}

// stats update for one 16-col chunk (Lraw includes bias)
template <bool GUARD>
static __device__ __forceinline__ void stats16(
    const float (&Lraw)[16], const f32x4* T4, int gcol0,
    float& ml, float& sl, float& mt, float& st, float& dd) {
  float Lv[16], Tv[16];
  #pragma unroll
  for (int k = 0; k < 16; ++k) {
    const bool ok = !GUARD || (gcol0 + k < V_DIM);
    Lv[k] = ok ? Lraw[k] : -1e30f;
    Tv[k] = ok ? T4[k >> 2][k & 3] : -1e30f;
  }
  float g = Lv[0];
  #pragma unroll
  for (int k = 1; k < 16; ++k) g = fmaxf(g, Lv[k]);
  if (g > ml + 12.f) { sl *= exp2f((ml - g) * LOG2E); ml = g; }
  float bl = ml * LOG2E;
  float ss = 0.f;
  #pragma unroll
  for (int k = 0; k < 16; ++k) ss += exp2f(__builtin_fmaf(Lv[k], LOG2E, -bl));
  sl += ss;
  float gt = Tv[0];
  #pragma unroll
  for (int k = 1; k < 16; ++k) gt = fmaxf(gt, Tv[k]);
  if (gt > mt + 12.f) {
    float sc = exp2f((mt - gt) * LOG2E);
    st *= sc; dd *= sc; mt = gt;
  }
  float bt = mt * LOG2E;
  float s2 = 0.f, d2 = 0.f;
  #pragma unroll
  for (int k = 0; k < 16; ++k) {
    float e = exp2f(__builtin_fmaf(Tv[k], LOG2E, -bt));
    s2 += e;
    d2 = __builtin_fmaf(e, Lv[k], d2);
  }
  st += s2; dd += d2;
}

// one 64-row stream pass: thread owns (row strow, 32-col quarter) = 2 chunks
template <bool GUARD>
static __device__ __forceinline__ void stream_pass(
    const f32x4 (&t)[8], const char* Lrow, int rsw, int obbase, int gc0,
    float& ml, float& sl, float& mt, float& st, float& dd) {
  #pragma unroll
  for (int ch = 0; ch < 2; ++ch) {
    const int ob = obbase + ch * 32;
    short8 l0 = *(const short8*)(Lrow + (ob ^ rsw));
    short8 l1 = *(const short8*)(Lrow + ((ob + 16) ^ rsw));
    float Lraw[16];
    #pragma unroll
    for (int e = 0; e < 8; ++e) {
      Lraw[e]     = __uint_as_float(((unsigned)(unsigned short)l0[e]) << 16);
      Lraw[e + 8] = __uint_as_float(((unsigned)(unsigned short)l1[e]) << 16);
    }
    stats16<GUARD>(Lraw, &t[ch * 4], gc0 + ch * 16, ml, sl, mt, st, dd);
  }
}

// ---------------- kernel B: fused GEMM + online softmax stats -------------
// Grid (32, 131). Block 256 = 4 waves (2x2, wave tile 64x64, acc 64).
// BK=32, FOUR rotating 16 KB staging buffers, stage issued 3 steps ahead
// (vmcnt(12) steady state -> staging latency fully hidden). ks=13..15 stage
// the next tile's k0..k2 (zero tile-boundary stall). L half-tile (16 KB,
// bf16, swizzled) on buffer 3; dump+stream in two 64-row passes.
__global__ __launch_bounds__(256, 2)
void fused_kernel(const __hip_bfloat16* __restrict__ Xb,
                  const __hip_bfloat16* __restrict__ Wb,
                  const float* __restrict__ bias,
                  const float* __restrict__ targets,
                  float* __restrict__ partials) {
  __shared__ __align__(16) char smem[65536];   // 4 x 16 KB bufs; L on buf3

  const int tid  = threadIdx.x;
  const int lane = tid & 63;
  const int wid  = tid >> 6;
  const int wm   = wid >> 1;
  const int wn   = wid & 1;
  const int q    = lane >> 4;
  const int c15  = lane & 15;
  const int brow = blockIdx.x;
  const int chunk = blockIdx.y;

  // two per-thread stats sets (pass0 row, pass1 row)
  float ml0 = -1e30f, sl0 = 0.f, mt0 = -1e30f, st0 = 0.f, dd0 = 0.f;
  float ml1 = -1e30f, sl1 = 0.f, mt1 = -1e30f, st1 = 0.f, dd1 = 0.f;

  // staging precompute: physical 16B unit p = site*256 + tid; row = p>>2,
  // slot c = p&3 holds logical k-slot q^ = c ^ (row&3) (XOR involution).
  const int srow = tid >> 2;                       // 0..63 (site adds +64)
  const int sq   = (tid & 3) ^ (srow & 3);
  const __hip_bfloat16* xsrc =
      Xb + (long)(brow * BM + srow) * H_DIM + sq * 8;
  const long woff = (long)srow * H_DIM + sq * 8;

  // fragment-read byte offsets (row&3 == c15&3 inside a 16-row frag group)
  const int xbyte = (wm * 64 + c15) * 64 + ((q ^ (c15 & 3)) * 16);
  const int wbyte = (wn * 64 + c15) * 64 + ((q ^ (c15 & 3)) * 16);

  // stream precompute: row = tid>>2 (0..63 local), quarter = tid&3
  const int quart = tid & 3;
  const int q32   = quart * 32;
  const int obb   = q32 * 2;
  const int rsw   = (srow & 15) << 4;
  const char* Lrow = smem + LOFF + srow * 256;
  const long tlim  = (long)N_ROWS * V_DIM - 4;

  auto stage = [&](int bufb, const __hip_bfloat16* wsrcp, int kk) {
    gload_lds16(xsrc + kk,                smem + bufb + tid * 16);
    gload_lds16(xsrc + 64 * H_DIM + kk,   smem + bufb + 4096 + tid * 16);
    gload_lds16(wsrcp + woff + kk,        smem + bufb + 8192 + tid * 16);
    gload_lds16(wsrcp + woff + 64 * H_DIM + kk,
                smem + bufb + 12288 + tid * 16);
  };

  // prologue: stage k0,k1,k2 of first tile into bufs 0,1,2
  const __hip_bfloat16* wsrc = Wb + (long)chunk * BN * H_DIM;
  stage(0, wsrc, 0);
  stage(16384, wsrc, BK);
  stage(32768, wsrc, 2 * BK);

  #pragma unroll 1
  for (int ti = 0; ti < 3; ++ti) {
    const int vt = chunk + ti * NCHUNK;
    const int vbase = vt * BN;
    const int v0 = vbase + wn * 64 + q * 4;
    const bool last = (ti == 2);
    const bool guard = (vt == VT_TOTAL - 1);
    const __hip_bfloat16* wsrc_next = Wb + (long)(vt + NCHUNK) * BN * H_DIM;

    f32x4 acc[4][4];
    #pragma unroll
    for (int a = 0; a < 4; ++a)
      #pragma unroll
      for (int b = 0; b < 4; ++b)
        acc[a][b] = (f32x4){0.f, 0.f, 0.f, 0.f};

    // ---- 16-step K-loop, 3-deep staging pipeline ----
    #pragma unroll
    for (int ks = 0; ks < NSTEP; ++ks) {
      const int bb = (ks & 3) << 14;
      const int pb = ((ks + 3) & 3) << 14;
      if (ks < 13)
        stage(pb, wsrc, (ks + 3) * BK);
      else if (!last)
        stage(pb, wsrc_next, (ks - 13) * BK);   // next-tile k0..k2

      if (ks < 13)       vmw<12>();
      else if (!last)    vmw<12>();
      else if (ks == 13) vmw<8>();
      else if (ks == 14) vmw<4>();
      else               vmw<0>();
      BARRIER();

      short8 xf[4], wf[4];
      #pragma unroll
      for (int a = 0; a < 4; ++a)
        xf[a] = *(const short8*)(smem + bb + xbyte + a * 1024);
      #pragma unroll
      for (int b = 0; b < 4; ++b)
        wf[b] = *(const short8*)(smem + bb + 8192 + wbyte + b * 1024);
      #pragma unroll
      for (int a = 0; a < 4; ++a)
        #pragma unroll
        for (int b = 0; b < 4; ++b)
          acc[a][b] = __builtin_amdgcn_mfma_f32_16x16x32_bf16(
              wf[b], xf[a], acc[a][b], 0, 0, 0);

      LGKM0();
      BARRIER();
    }
    wsrc = wsrc_next;

    // ---- epilogue: bias + T0 loads, then 2x (dump half + stream half) ----
    f32x4 bp[4];
    #pragma unroll
    for (int b = 0; b < 4; ++b) {
      int bo = v0 + b * 16;
      bo = bo > (V_DIM - 4) ? (V_DIM - 4) : bo;
      bp[b] = *(const f32x4*)(bias + bo);
    }
    auto loadT = [&](f32x4 (&t)[8], int h) {
      const long rb =
          (long)(brow * BM + h * 64 + srow) * V_DIM + vbase + q32;
      #pragma unroll
      for (int c = 0; c < 8; ++c) {
        long off = rb + c * 4;
        off = off > tlim ? tlim : off;
        t[c] = *(const f32x4*)(targets + off);
      }
    };
    auto dump_half = [&]() {   // waves of the selected wm write local rows
      #pragma unroll
      for (int a = 0; a < 4; ++a) {
        const int r = a * 16 + c15;
        char* rb = smem + LOFF + r * 256;
        const int rw = (r & 15) << 4;
        #pragma unroll
        for (int b = 0; b < 4; ++b) {
          uint2 w;
          w.x = (unsigned)f2bf(acc[a][b][0] + bp[b][0]) |
                ((unsigned)f2bf(acc[a][b][1] + bp[b][1]) << 16);
          w.y = (unsigned)f2bf(acc[a][b][2] + bp[b][2]) |
                ((unsigned)f2bf(acc[a][b][3] + bp[b][3]) << 16);
          const int o = wn * 128 + b * 32 + q * 8;
          *(uint2*)(rb + (o ^ rw)) = w;
        }
      }
    };

    f32x4 t0[8];
    loadT(t0, 0);
    if (wm == 0) dump_half();
    LGKM0();
    BARRIER();
    VMC0();                    // t0 (and any in-flight prefetch) arrived
    f32x4 t1[8];
    loadT(t1, 1);              // hides under stream pass 0
    if (guard)
      stream_pass<true >(t0, Lrow, rsw, obb, vbase + q32, ml0, sl0, mt0, st0, dd0);
    else
      stream_pass<false>(t0, Lrow, rsw, obb, vbase + q32, ml0, sl0, mt0, st0, dd0);
    LGKM0();
    BARRIER();
    if (wm == 1) dump_half();
    LGKM0();
    BARRIER();
    VMC0();                    // t1 arrived
    if (guard)
      stream_pass<true >(t1, Lrow, rsw, obb, vbase + q32, ml1, sl1, mt1, st1, dd1);
    else
      stream_pass<false>(t1, Lrow, rsw, obb, vbase + q32, ml1, sl1, mt1, st1, dd1);
    LGKM0();
    BARRIER();                 // L reads done; next tile stages over buf3
  }

  // merge the four quarters of each row (lane bits 0,1), both stats sets
  #pragma unroll
  for (int off = 1; off <= 2; off <<= 1) {
    {
      float ml2 = __shfl_xor(ml0, off), sl2 = __shfl_xor(sl0, off);
      float mt2 = __shfl_xor(mt0, off), st2 = __shfl_xor(st0, off);
      float dd2 = __shfl_xor(dd0, off);
      float nm = fmaxf(ml0, ml2);
      sl0 = sl0 * exp2f((ml0 - nm) * LOG2E) + sl2 * exp2f((ml2 - nm) * LOG2E);
      ml0 = nm;
      float nmt = fmaxf(mt0, mt2);
      float e1 = exp2f((mt0 - nmt) * LOG2E), e2 = exp2f((mt2 - nmt) * LOG2E);
      st0 = st0 * e1 + st2 * e2;
      dd0 = dd0 * e1 + dd2 * e2;
      mt0 = nmt;
    }
    {
      float ml2 = __shfl_xor(ml1, off), sl2 = __shfl_xor(sl1, off);
      float mt2 = __shfl_xor(mt1, off), st2 = __shfl_xor(st1, off);
      float dd2 = __shfl_xor(dd1, off);
      float nm = fmaxf(ml1, ml2);
      sl1 = sl1 * exp2f((ml1 - nm) * LOG2E) + sl2 * exp2f((ml2 - nm) * LOG2E);
      ml1 = nm;
      float nmt = fmaxf(mt1, mt2);
      float e1 = exp2f((mt1 - nmt) * LOG2E), e2 = exp2f((mt2 - nmt) * LOG2E);
      st1 = st1 * e1 + st2 * e2;
      dd1 = dd1 * e1 + dd2 * e2;
      mt1 = nmt;
    }
  }
  if (quart == 0) {
    long r0 = (long)(brow * BM + srow);
    float* o = partials + (r0 * NCHUNK + chunk) * 5;
    o[0] = ml0; o[1] = sl0; o[2] = mt0; o[3] = st0; o[4] = dd0;
    float* o1 = partials + ((r0 + 64) * NCHUNK + chunk) * 5;
    o1[0] = ml1; o1[1] = sl1; o1[2] = mt1; o1[3] = st1; o1[4] = dd1;
  }
}

// ---------------- kernel C: merge partials -> per-row loss ----------------
__global__ void rowloss_kernel(const float* __restrict__ partials,
                               float* __restrict__ rowloss) {
  int r = blockIdx.x * blockDim.x + threadIdx.x;
  if (r >= N_ROWS) return;
  const float* p = partials + (long)r * NCHUNK * 5;
  float ml = -1e30f, sl = 0.f, mt = -1e30f, st = 0.f, dd = 0.f;
  for (int c = 0; c < NCHUNK; ++c) {
    float ml2 = p[0], sl2 = p[1], mt2 = p[2], st2 = p[3], dd2 = p[4];
    p += 5;
    float nm = fmaxf(ml, ml2);
    sl = sl * exp2f((ml - nm) * LOG2E) + sl2 * exp2f((ml2 - nm) * LOG2E);
    ml = nm;
    float nmt = fmaxf(mt, mt2);
    float e1 = exp2f((mt - nmt) * LOG2E);
    float e2 = exp2f((mt2 - nmt) * LOG2E);
    st = st * e1 + st2 * e2;
    dd = dd * e1 + dd2 * e2;
    mt = nmt;
  }
  float lse = ml + logf(sl);
  rowloss[r] = lse - dd / st;
}

// ---------------- kernel D: final scalar reduce ---------------------------
__global__ void final_kernel(const float* __restrict__ rowloss,
                             float* __restrict__ out) {
  __shared__ float sm[4];
  float s = 0.f;
  for (int i = threadIdx.x; i < N_ROWS; i += 256) s += rowloss[i];
  #pragma unroll
  for (int off = 32; off > 0; off >>= 1) s += __shfl_down(s, off);
  if ((threadIdx.x & 63) == 0) sm[threadIdx.x >> 6] = s;
  __syncthreads();
  if (threadIdx.x == 0) out[0] = (sm[0] + sm[1] + sm[2] + sm[3]) * (1.0f / (float)N_ROWS);
}

extern "C" void kernel_launch(void* const* d_in, const int* in_sizes, int n_in,
                              void* d_out, int out_size, void* d_ws, size_t ws_size,
                              hipStream_t stream) {
  const float* x       = (const float*)d_in[0];   // [4096, 512]
  const float* targets = (const float*)d_in[1];   // [4096, 50257]
  const float* weight  = (const float*)d_in[2];   // [50257, 512]
  const float* bias    = (const float*)d_in[3];   // [50257]
  float* out = (float*)d_out;

  char* ws = (char*)d_ws;
  __hip_bfloat16* Wb = (__hip_bfloat16*)ws;                     // 51,511,296 B
  size_t off = (size_t)V_PAD * H_DIM * 2;
  __hip_bfloat16* Xb = (__hip_bfloat16*)(ws + off);             //  4,194,304 B
  off += (size_t)N_ROWS * H_DIM * 2;
  float* partials = (float*)(ws + off);                         // 10,731,520 B
  off += (size_t)N_ROWS * NCHUNK * 5 * sizeof(float);
  float* rowloss = (float*)(ws + off);                          //     16,384 B

  convert_kernel<<<13600, 256, 0, stream>>>(x, weight, Xb, Wb);
  dim3 grid(N_ROWS / BM, NCHUNK);
  fused_kernel<<<grid, 256, 0, stream>>>(Xb, Wb, bias, targets, partials);
  rowloss_kernel<<<N_ROWS / 256, 256, 0, stream>>>(partials, rowloss);
  final_kernel<<<1, 256, 0, stream>>>(rowloss, out);
}